// Round 7
// baseline (342.554 us; speedup 1.0000x reference)
//
#include <hip/hip_runtime.h>
#include <cstdint>

#define B 32
#define L 512
#define T 2048
#define M 80
#define KDIM 160

#define NEG_INF (-1e30f)
#define LOG_2PI 1.8378770664093453f

typedef float f32x4 __attribute__((ext_vector_type(4)));

// robust to harness passing lengths as int32 or int64 (values are small positive;
// if int64, word[1] == high word of elem0 == 0; if int32, word[1] in [64,2048] != 0)
__device__ __forceinline__ int get_len(const int* __restrict__ p, int b) {
  return (p[1] == 0) ? p[2 * b] : p[b];
}

// ---------------- prep: Wmat[b][k][l], bias[b][l] ----------------
__global__ __launch_bounds__(256) void prep_kernel(const float* __restrict__ mu_sigma,
                                                   float* __restrict__ Wmat,
                                                   float* __restrict__ biasv) {
  int gid = blockIdx.x * 256 + threadIdx.x;  // b*L + l
  if (gid >= B * L) return;
  int b = gid >> 9;
  int l = gid & (L - 1);
  const float* row = mu_sigma + (size_t)gid * (2 * M);
  float* wb = Wmat + (size_t)b * KDIM * L + l;
  float acc_a = 0.f, acc_ls = 0.f;
#pragma unroll 4
  for (int m = 0; m < M; ++m) {
    float mu = row[m];
    float ls = row[M + m];
    float iv = expf(-2.f * ls);
    acc_a += mu * mu * iv;
    acc_ls += ls;
    wb[(size_t)m * L] = -0.5f * iv;
    wb[(size_t)(M + m) * L] = mu * iv;
  }
  biasv[gid] = -0.5f * acc_a - (0.5f * (float)M * LOG_2PI + 0.5f * acc_ls);
}

// ---------------- gemm: logpT[b][t][l] = bias[l] + sum_k X[k][t]*W[k][l] ----------------
#define LT 64
#define LL 64
#define KC 40
__global__ __launch_bounds__(256) void gemm_logp(const float* __restrict__ x,
                                                 const float* __restrict__ Wmat,
                                                 const float* __restrict__ biasv,
                                                 const int* __restrict__ mel_len,
                                                 const int* __restrict__ text_len,
                                                 float* __restrict__ logpT,
                                                 int t_begin, int tc) {
  int b = blockIdx.z;
  int t0 = t_begin + blockIdx.x * LT;
  int l0 = blockIdx.y * LL;
  if (t0 >= get_len(mel_len, b)) return;
  if (l0 >= get_len(text_len, b)) return;

  __shared__ float Xs[KC][LT];
  __shared__ float Ws[KC][LL];
  int tid = threadIdx.x;
  int tx = tid & 15;   // t quad
  int ly = tid >> 4;   // l quad

  float acc[4][4];
#pragma unroll
  for (int i = 0; i < 4; ++i)
#pragma unroll
    for (int j = 0; j < 4; ++j) acc[i][j] = 0.f;

  for (int kc = 0; kc < KDIM; kc += KC) {
    bool sq = (kc < M);
#pragma unroll
    for (int p = 0; p < (KC * LT) / 256; ++p) {  // 10 passes
      int idx = p * 256 + tid;
      int kk = idx >> 6;
      int cc = idx & 63;
      int k = kc + kk;
      int m = sq ? k : (k - M);
      float xv = x[((size_t)b * M + m) * T + t0 + cc];
      Xs[kk][cc] = sq ? xv * xv : xv;
      Ws[kk][cc] = Wmat[((size_t)b * KDIM + k) * L + l0 + cc];
    }
    __syncthreads();
#pragma unroll 8
    for (int k = 0; k < KC; ++k) {
      float xa[4], wa[4];
#pragma unroll
      for (int i = 0; i < 4; ++i) xa[i] = Xs[k][tx * 4 + i];
#pragma unroll
      for (int j = 0; j < 4; ++j) wa[j] = Ws[k][ly * 4 + j];
#pragma unroll
      for (int i = 0; i < 4; ++i)
#pragma unroll
        for (int j = 0; j < 4; ++j) acc[i][j] += xa[i] * wa[j];
    }
    __syncthreads();
  }

  float bb[4];
#pragma unroll
  for (int j = 0; j < 4; ++j) bb[j] = biasv[b * L + l0 + ly * 4 + j];
#pragma unroll
  for (int i = 0; i < 4; ++i) {
    int t = t0 + tx * 4 + i;
    float4 v;
    v.x = acc[i][0] + bb[0];
    v.y = acc[i][1] + bb[1];
    v.z = acc[i][2] + bb[2];
    v.w = acc[i][3] + bb[3];
    *(float4*)(logpT + ((size_t)b * tc + (t - t_begin)) * L + l0 + ly * 4) = v;
  }
}

// ---------------- scan: one wave per batch, max-plus recursion ----------------
// Lane i owns l in [4i,4i+4) (c0) and [256+4i,256+4i+4) (c1). No LDS at all:
// rows go global -> 48 NAMED f32x4 registers (3 blocks of 8 rows, inline-asm
// global_load_dwordx4), retired with counted vmcnt(46-2r) waits (vmcnt counts
// to 63, unlike lgkmcnt's 15). Neighbor values via DPP (pure VALU).
#define GLD0(dst, p) \
  asm volatile("global_load_dwordx4 %0, %1, off" : "=v"(dst) : "v"(p))
#define GLD1(dst, p) \
  asm volatile("global_load_dwordx4 %0, %1, off offset:1024" : "=v"(dst) : "v"(p))
#define VMW(n)                                             \
  do {                                                     \
    asm volatile("s_waitcnt vmcnt(" #n ")" ::: "memory");  \
    __builtin_amdgcn_sched_barrier(0);                     \
  } while (0)

#define DECL_BLK(P) \
  f32x4 P##0a, P##0b, P##1a, P##1b, P##2a, P##2b, P##3a, P##3b, \
        P##4a, P##4b, P##5a, P##5b, P##6a, P##6b, P##7a, P##7b

#define LOAD_BLK(P, i_)                                                     \
  do {                                                                      \
    int t0_ = tstart + 8 * (i_);                                            \
    const float* p0_ = baseLane + (size_t)(min(t0_ + 0, tlast) - t_begin) * L; \
    const float* p1_ = baseLane + (size_t)(min(t0_ + 1, tlast) - t_begin) * L; \
    const float* p2_ = baseLane + (size_t)(min(t0_ + 2, tlast) - t_begin) * L; \
    const float* p3_ = baseLane + (size_t)(min(t0_ + 3, tlast) - t_begin) * L; \
    const float* p4_ = baseLane + (size_t)(min(t0_ + 4, tlast) - t_begin) * L; \
    const float* p5_ = baseLane + (size_t)(min(t0_ + 5, tlast) - t_begin) * L; \
    const float* p6_ = baseLane + (size_t)(min(t0_ + 6, tlast) - t_begin) * L; \
    const float* p7_ = baseLane + (size_t)(min(t0_ + 7, tlast) - t_begin) * L; \
    GLD0(P##0a, p0_); GLD1(P##0b, p0_);                                     \
    GLD0(P##1a, p1_); GLD1(P##1b, p1_);                                     \
    GLD0(P##2a, p2_); GLD1(P##2b, p2_);                                     \
    GLD0(P##3a, p3_); GLD1(P##3b, p3_);                                     \
    GLD0(P##4a, p4_); GLD1(P##4b, p4_);                                     \
    GLD0(P##5a, p5_); GLD1(P##5b, p5_);                                     \
    GLD0(P##6a, p6_); GLD1(P##6b, p6_);                                     \
    GLD0(P##7a, p7_); GLD1(P##7b, p7_);                                     \
  } while (0)

#define COMP_BLK(P, i_)                                   \
  do {                                                    \
    int nr_ = tstop - (tstart + 8 * (i_));                \
    if (nr_ >= 8) {                                       \
      VMW(46); step(P##0a, P##0b);                        \
      VMW(44); step(P##1a, P##1b);                        \
      VMW(42); step(P##2a, P##2b);                        \
      VMW(40); step(P##3a, P##3b);                        \
      VMW(38); step(P##4a, P##4b);                        \
      VMW(36); step(P##5a, P##5b);                        \
      VMW(34); step(P##6a, P##6b);                        \
      VMW(32); step(P##7a, P##7b);                        \
    } else {                                              \
      VMW(0);                                             \
      if (nr_ > 0) step(P##0a, P##0b);                    \
      if (nr_ > 1) step(P##1a, P##1b);                    \
      if (nr_ > 2) step(P##2a, P##2b);                    \
      if (nr_ > 3) step(P##3a, P##3b);                    \
      if (nr_ > 4) step(P##4a, P##4b);                    \
      if (nr_ > 5) step(P##5a, P##5b);                    \
      if (nr_ > 6) step(P##6a, P##6b);                    \
    }                                                     \
  } while (0)

__device__ __forceinline__ float dpp_shr1_neginf(float x) {
  int r = __builtin_amdgcn_update_dpp(__float_as_int(NEG_INF), __float_as_int(x),
                                      0x138, 0xf, 0xf, false);  // wave_shr:1
  return __int_as_float(r);
}
__device__ __forceinline__ float dpp_ror1(float x) {
  int r = __builtin_amdgcn_update_dpp(0, __float_as_int(x),
                                      0x13C, 0xf, 0xf, false);  // wave_ror:1
  return __int_as_float(r);
}

__global__ __launch_bounds__(64, 1) void scan_kernel(const float* __restrict__ logpT,
                                                     const int* __restrict__ mel_len,
                                                     const int* __restrict__ text_len,
                                                     float* __restrict__ carry_ws,
                                                     float* __restrict__ la_ws,
                                                     int t_begin, int tc) {
  int b = blockIdx.x;
  int lane = threadIdx.x;
  int ml = get_len(mel_len, b);
  int tl = get_len(text_len, b);
  const float* base0 = logpT + (size_t)b * tc * L;
  const float* baseLane = base0 + 4 * lane;
  float* cws = carry_ws + b * L;
  bool is63 = (lane == 63);

  float c0[4], c1[4];
  int tstart;
  if (t_begin == 0) {
#pragma unroll
    for (int j = 0; j < 4; ++j) { c0[j] = NEG_INF; c1[j] = NEG_INF; }
    if (lane == 0) c0[0] = base0[0];  // logp[b,0,0] at l=0
    tstart = 1;
  } else {
    float4 v0 = *(const float4*)(cws + 4 * lane);
    float4 v1 = *(const float4*)(cws + 256 + 4 * lane);
    c0[0] = v0.x; c0[1] = v0.y; c0[2] = v0.z; c0[3] = v0.w;
    c1[0] = v1.x; c1[1] = v1.y; c1[2] = v1.z; c1[3] = v1.w;
    tstart = t_begin;
  }

  int tstop = min(t_begin + tc, ml);
  int tlast = tstop - 1;

  auto step = [&](f32x4 l0, f32x4 l1) {
    float pb0 = dpp_shr1_neginf(c0[3]);        // lane i-1's c0[3] (old)
    float merged = is63 ? c0[3] : c1[3];
    float pb1 = dpp_ror1(merged);              // lane i-1's c1[3]; lane0 <- lane63 c0[3]
    c1[3] = fmaxf(c1[3], c1[2]) + l1[3];
    c1[2] = fmaxf(c1[2], c1[1]) + l1[2];
    c1[1] = fmaxf(c1[1], c1[0]) + l1[1];
    c1[0] = fmaxf(c1[0], pb1) + l1[0];
    c0[3] = fmaxf(c0[3], c0[2]) + l0[3];
    c0[2] = fmaxf(c0[2], c0[1]) + l0[2];
    c0[1] = fmaxf(c0[1], c0[0]) + l0[1];
    c0[0] = fmaxf(c0[0], pb0) + l0[0];
  };

  int nb = (tstop > tstart) ? ((tstop - tstart + 7) / 8) : 0;
  if (nb > 0) {
    DECL_BLK(A);
    DECL_BLK(Bk);
    DECL_BLK(C);
    LOAD_BLK(A, 0);
    LOAD_BLK(Bk, min(1, nb - 1));
    LOAD_BLK(C, min(2, nb - 1));
    int i = 0;
    for (;;) {
      COMP_BLK(A, i);
      if (i + 1 >= nb) break;
      LOAD_BLK(A, min(i + 3, nb - 1));
      ++i;
      COMP_BLK(Bk, i);
      if (i + 1 >= nb) break;
      LOAD_BLK(Bk, min(i + 3, nb - 1));
      ++i;
      COMP_BLK(C, i);
      if (i + 1 >= nb) break;
      LOAD_BLK(C, min(i + 3, nb - 1));
      ++i;
    }
    asm volatile("s_waitcnt vmcnt(0)" ::: "memory");  // drain dup prefetches
  }

  // persist carry for next chunk (natural-l layout)
  *(float4*)(cws + 4 * lane) = make_float4(c0[0], c0[1], c0[2], c0[3]);
  *(float4*)(cws + 256 + 4 * lane) = make_float4(c1[0], c1[1], c1[2], c1[3]);

  if (t_begin + tc >= T) {  // last chunk: la[b] = alpha[ml-1][tl-1]
    int li = tl - 1;
    int sub = li & 3;
    float v0 = (sub == 0) ? c0[0] : (sub == 1) ? c0[1] : (sub == 2) ? c0[2] : c0[3];
    float v1 = (sub == 0) ? c1[0] : (sub == 1) ? c1[1] : (sub == 2) ? c1[2] : c1[3];
    float v = (li < 256) ? v0 : v1;
    int sl = (li < 256) ? (li >> 2) : ((li - 256) >> 2);
    float lav = __shfl(v, sl);
    if (lane == 0) la_ws[b] = lav;
  }
}

__global__ __launch_bounds__(64) void reduce_kernel(const float* __restrict__ la_ws,
                                                    float* __restrict__ out) {
  int lane = threadIdx.x;
  float v = (lane < B) ? la_ws[lane] : 0.f;
#pragma unroll
  for (int s = 32; s > 0; s >>= 1) v += __shfl_down(v, s);
  if (lane == 0) out[0] = -v * (1.0f / (float)B);
}

extern "C" void kernel_launch(void* const* d_in, const int* in_sizes, int n_in,
                              void* d_out, int out_size, void* d_ws, size_t ws_size,
                              hipStream_t stream) {
  const float* mu_sigma = (const float*)d_in[0];
  const float* melspec  = (const float*)d_in[1];
  const int*   text_len = (const int*)d_in[2];
  const int*   mel_len  = (const int*)d_in[3];
  float* out = (float*)d_out;

  char* ws = (char*)d_ws;
  size_t off = 0;
  float* Wmat = (float*)(ws + off);      off += (size_t)B * KDIM * L * 4;  // 10.5 MB
  float* biasv = (float*)(ws + off);     off += (size_t)B * L * 4;
  float* carry_ws = (float*)(ws + off);  off += (size_t)B * L * 4;
  float* la_ws = (float*)(ws + off);     off += 256;
  float* logpT = (float*)(ws + off);
  size_t avail = (ws_size > off) ? (ws_size - off) : 0;
  size_t per_t = (size_t)B * L * 4;  // bytes per t-slice across all b
  long long tcl = (long long)(avail / per_t);
  int Tc = (tcl > T) ? T : (int)tcl;
  Tc &= ~63;
  if (Tc < 64) return;  // insufficient workspace (not expected)

  prep_kernel<<<dim3((B * L + 255) / 256), 256, 0, stream>>>(mu_sigma, Wmat, biasv);

  for (int t_begin = 0; t_begin < T; t_begin += Tc) {
    int tc = (T - t_begin < Tc) ? (T - t_begin) : Tc;
    dim3 grid(tc / LT, L / LL, B);
    gemm_logp<<<grid, 256, 0, stream>>>(melspec, Wmat, biasv, mel_len, text_len,
                                        logpT, t_begin, tc);
    scan_kernel<<<dim3(B), 64, 0, stream>>>(logpT, mel_len, text_len, carry_ws,
                                            la_ws, t_begin, tc);
  }
  reduce_kernel<<<1, 64, 0, stream>>>(la_ws, out);
}

// Round 8
// 336.635 us; speedup vs baseline: 1.0176x; 1.0176x over previous
//
#include <hip/hip_runtime.h>
#include <hip/hip_bf16.h>
#include <cstdint>

#define B 32
#define L 512
#define T 2048
#define M 80
#define KDIM 160

#define NEG_INF (-1e30f)
#define LOG_2PI 1.8378770664093453f

typedef uint32_t u32;
typedef u32 u32x4 __attribute__((ext_vector_type(4)));

// robust to harness passing lengths as int32 or int64 (values are small positive;
// if int64, word[1] == high word of elem0 == 0; if int32, word[1] in [64,2048] != 0)
__device__ __forceinline__ int get_len(const int* __restrict__ p, int b) {
  return (p[1] == 0) ? p[2 * b] : p[b];
}

__device__ __forceinline__ unsigned short f2bf(float f) {
  __hip_bfloat16 h = __float2bfloat16(f);
  return *(unsigned short*)&h;
}

// ---------------- prep: Wmat[b][k][l], bias[b][l] ----------------
__global__ __launch_bounds__(256) void prep_kernel(const float* __restrict__ mu_sigma,
                                                   float* __restrict__ Wmat,
                                                   float* __restrict__ biasv) {
  int gid = blockIdx.x * 256 + threadIdx.x;  // b*L + l
  if (gid >= B * L) return;
  int b = gid >> 9;
  int l = gid & (L - 1);
  const float* row = mu_sigma + (size_t)gid * (2 * M);
  float* wb = Wmat + (size_t)b * KDIM * L + l;
  float acc_a = 0.f, acc_ls = 0.f;
#pragma unroll 4
  for (int m = 0; m < M; ++m) {
    float mu = row[m];
    float ls = row[M + m];
    float iv = expf(-2.f * ls);
    acc_a += mu * mu * iv;
    acc_ls += ls;
    wb[(size_t)m * L] = -0.5f * iv;
    wb[(size_t)(M + m) * L] = mu * iv;
  }
  biasv[gid] = -0.5f * acc_a - (0.5f * (float)M * LOG_2PI + 0.5f * acc_ls);
}

// ---------------- gemm: logpT[b][t][l] (bf16) = bias[l] + sum_k X[k][t]*W[k][l] ----
#define LT 64
#define LL 64
#define KC 40
__global__ __launch_bounds__(256) void gemm_logp(const float* __restrict__ x,
                                                 const float* __restrict__ Wmat,
                                                 const float* __restrict__ biasv,
                                                 const int* __restrict__ mel_len,
                                                 const int* __restrict__ text_len,
                                                 unsigned short* __restrict__ logpT,
                                                 int t_begin, int tc) {
  int b = blockIdx.z;
  int t0 = t_begin + blockIdx.x * LT;
  int l0 = blockIdx.y * LL;
  if (t0 >= get_len(mel_len, b)) return;
  if (l0 >= get_len(text_len, b)) return;

  __shared__ float Xs[KC][LT];
  __shared__ float Ws[KC][LL];
  int tid = threadIdx.x;
  int tx = tid & 15;   // t quad
  int ly = tid >> 4;   // l quad

  float acc[4][4];
#pragma unroll
  for (int i = 0; i < 4; ++i)
#pragma unroll
    for (int j = 0; j < 4; ++j) acc[i][j] = 0.f;

  for (int kc = 0; kc < KDIM; kc += KC) {
    bool sq = (kc < M);
#pragma unroll
    for (int p = 0; p < (KC * LT) / 256; ++p) {  // 10 passes
      int idx = p * 256 + tid;
      int kk = idx >> 6;
      int cc = idx & 63;
      int k = kc + kk;
      int m = sq ? k : (k - M);
      float xv = x[((size_t)b * M + m) * T + t0 + cc];
      Xs[kk][cc] = sq ? xv * xv : xv;
      Ws[kk][cc] = Wmat[((size_t)b * KDIM + k) * L + l0 + cc];
    }
    __syncthreads();
#pragma unroll 8
    for (int k = 0; k < KC; ++k) {
      float xa[4], wa[4];
#pragma unroll
      for (int i = 0; i < 4; ++i) xa[i] = Xs[k][tx * 4 + i];
#pragma unroll
      for (int j = 0; j < 4; ++j) wa[j] = Ws[k][ly * 4 + j];
#pragma unroll
      for (int i = 0; i < 4; ++i)
#pragma unroll
        for (int j = 0; j < 4; ++j) acc[i][j] += xa[i] * wa[j];
    }
    __syncthreads();
  }

  float bb[4];
#pragma unroll
  for (int j = 0; j < 4; ++j) bb[j] = biasv[b * L + l0 + ly * 4 + j];
#pragma unroll
  for (int i = 0; i < 4; ++i) {
    int t = t0 + tx * 4 + i;
    ushort4 o;
    o.x = f2bf(acc[i][0] + bb[0]);
    o.y = f2bf(acc[i][1] + bb[1]);
    o.z = f2bf(acc[i][2] + bb[2]);
    o.w = f2bf(acc[i][3] + bb[3]);
    *(ushort4*)(logpT + ((size_t)b * tc + (t - t_begin)) * L + l0 + ly * 4) = o;
  }
}

// ---------------- scan: one wave per batch, max-plus recursion, bf16 logp ------
// Lane i owns l = 8i..8i+7 (one ds_read_b128 = 8 bf16, 16B lane stride ->
// conflict-free). 6-deep stage pipeline (8 x global_load_lds of 1KB per 8-row
// block, counted vmcnt), counted lgkmcnt per row, DPP wave_shr boundary.
#define SB 8
#define NBUF 8
#define PF 6

#define DS_READ_B128U(dst, addr, imm) \
  asm volatile("ds_read_b128 %0, %1 offset:" #imm : "=v"(dst) : "v"(addr))
#define LGKM(n)                                             \
  do {                                                      \
    asm volatile("s_waitcnt lgkmcnt(" #n ")" ::: "memory"); \
    __builtin_amdgcn_sched_barrier(0);                      \
  } while (0)
#define VMW(n)                                             \
  do {                                                     \
    asm volatile("s_waitcnt vmcnt(" #n ")" ::: "memory");  \
    __builtin_amdgcn_sched_barrier(0);                     \
  } while (0)

__device__ __forceinline__ float dpp_shr1_neginf(float x) {
  int r = __builtin_amdgcn_update_dpp(__float_as_int(NEG_INF), __float_as_int(x),
                                      0x138, 0xf, 0xf, false);  // wave_shr:1
  return __int_as_float(r);
}

__global__ __launch_bounds__(64) void scan_kernel(const unsigned short* __restrict__ logpT,
                                                  const int* __restrict__ mel_len,
                                                  const int* __restrict__ text_len,
                                                  float* __restrict__ carry_ws,
                                                  float* __restrict__ la_ws,
                                                  int t_begin, int tc) {
  __shared__ unsigned short lds[NBUF][SB][L];  // 64 KB
  int b = blockIdx.x;
  int lane = threadIdx.x;
  int ml = get_len(mel_len, b);
  int tl = get_len(text_len, b);
  const unsigned short* base0 = logpT + (size_t)b * tc * L;
  float* cws = carry_ws + b * L + lane * 8;

  float c[8];
  int tstart;
  if (t_begin == 0) {
#pragma unroll
    for (int j = 0; j < 8; ++j) c[j] = NEG_INF;
    if (lane == 0) c[0] = __uint_as_float((u32)base0[0] << 16);  // logp[b,0,0]
    tstart = 1;
  } else {
    float4 v0 = *(const float4*)(cws);
    float4 v1 = *(const float4*)(cws + 4);
    c[0] = v0.x; c[1] = v0.y; c[2] = v0.z; c[3] = v0.w;
    c[4] = v1.x; c[5] = v1.y; c[6] = v1.z; c[7] = v1.w;
    tstart = t_begin;
  }

  int tstop = min(t_begin + tc, ml);

  auto stepu = [&](u32x4 v) {
    float p = dpp_shr1_neginf(c[7]);  // lane i-1's old c[7]; lane0 <- NEG_INF
    float f0 = __uint_as_float(v[0] << 16);
    float f1 = __uint_as_float(v[0] & 0xFFFF0000u);
    float f2 = __uint_as_float(v[1] << 16);
    float f3 = __uint_as_float(v[1] & 0xFFFF0000u);
    float f4 = __uint_as_float(v[2] << 16);
    float f5 = __uint_as_float(v[2] & 0xFFFF0000u);
    float f6 = __uint_as_float(v[3] << 16);
    float f7 = __uint_as_float(v[3] & 0xFFFF0000u);
    c[7] = fmaxf(c[7], c[6]) + f7;
    c[6] = fmaxf(c[6], c[5]) + f6;
    c[5] = fmaxf(c[5], c[4]) + f5;
    c[4] = fmaxf(c[4], c[3]) + f4;
    c[3] = fmaxf(c[3], c[2]) + f3;
    c[2] = fmaxf(c[2], c[1]) + f2;
    c[1] = fmaxf(c[1], c[0]) + f1;
    c[0] = fmaxf(c[0], p) + f0;
  };

  int nb = (tstop > tstart) ? ((tstop - tstart + SB - 1) / SB) : 0;
  if (nb > 0) {
    auto stage = [&](int i) {
      if (i >= nb) return;
      int tb = tstart + i * SB;
      unsigned short* dstb = &lds[i & (NBUF - 1)][0][0];
      if (tb + SB <= tstop) {
#pragma unroll
        for (int u = 0; u < SB; ++u) {
          const unsigned short* s = base0 + (size_t)(tb + u - t_begin) * L;
          __builtin_amdgcn_global_load_lds(
              (const __attribute__((address_space(1))) void*)(s + lane * 8),
              (__attribute__((address_space(3))) void*)(dstb + (size_t)u * L),
              16, 0, 0);
        }
      } else {
#pragma unroll
        for (int u = 0; u < SB; ++u) {
          int row = min(tb + u, tstop - 1) - t_begin;
          const unsigned short* s = base0 + (size_t)row * L;
          __builtin_amdgcn_global_load_lds(
              (const __attribute__((address_space(1))) void*)(s + lane * 8),
              (__attribute__((address_space(3))) void*)(dstb + (size_t)u * L),
              16, 0, 0);
        }
      }
    };
#pragma unroll
    for (int s = 0; s < PF; ++s) stage(s);
    for (int i = 0; i < nb; ++i) {
      stage(i + PF);
      int rem = nb - 1 - i;
      if (rem > PF) rem = PF;
      if (rem >= 6)      VMW(48);
      else if (rem == 5) VMW(40);
      else if (rem == 4) VMW(32);
      else if (rem == 3) VMW(24);
      else if (rem == 2) VMW(16);
      else if (rem == 1) VMW(8);
      else               VMW(0);
      int tb = tstart + i * SB;
      u32 basea = (u32)(uintptr_t)(__attribute__((address_space(3)))
                                   unsigned short*)(&lds[i & (NBUF - 1)][0][0]) +
                  16u * (u32)lane;
      if (tb + SB <= tstop) {
        u32x4 r0, r1, r2, r3, r4, r5, r6, r7;
        DS_READ_B128U(r0, basea, 0);
        DS_READ_B128U(r1, basea, 1024);
        DS_READ_B128U(r2, basea, 2048);
        DS_READ_B128U(r3, basea, 3072);
        DS_READ_B128U(r4, basea, 4096);
        DS_READ_B128U(r5, basea, 5120);
        DS_READ_B128U(r6, basea, 6144);
        DS_READ_B128U(r7, basea, 7168);
        LGKM(7); stepu(r0);
        LGKM(6); stepu(r1);
        LGKM(5); stepu(r2);
        LGKM(4); stepu(r3);
        LGKM(3); stepu(r4);
        LGKM(2); stepu(r5);
        LGKM(1); stepu(r6);
        LGKM(0); stepu(r7);
      } else {
        int e = tstop - tb;  // 1..SB-1 (only the last block)
        const u32* rp = (const u32*)(&lds[i & (NBUF - 1)][0][0]) + lane * 4;
        for (int t = 0; t < e; ++t) {
          u32x4 v = *(const u32x4*)(rp + (size_t)t * (L / 2));
          stepu(v);
        }
      }
    }
  }

  // persist carry for next chunk
  *(float4*)(cws) = make_float4(c[0], c[1], c[2], c[3]);
  *(float4*)(cws + 4) = make_float4(c[4], c[5], c[6], c[7]);

  if (t_begin + tc >= T) {  // last chunk: la[b] = alpha[ml-1][tl-1]
    int li = tl - 1;
    float csel = NEG_INF;
#pragma unroll
    for (int j = 0; j < 8; ++j)
      if ((li & 7) == j) csel = c[j];
    float lav = __shfl(csel, li >> 3);
    if (lane == 0) la_ws[b] = lav;
  }
}

__global__ __launch_bounds__(64) void reduce_kernel(const float* __restrict__ la_ws,
                                                    float* __restrict__ out) {
  int lane = threadIdx.x;
  float v = (lane < B) ? la_ws[lane] : 0.f;
#pragma unroll
  for (int s = 32; s > 0; s >>= 1) v += __shfl_down(v, s);
  if (lane == 0) out[0] = -v * (1.0f / (float)B);
}

extern "C" void kernel_launch(void* const* d_in, const int* in_sizes, int n_in,
                              void* d_out, int out_size, void* d_ws, size_t ws_size,
                              hipStream_t stream) {
  const float* mu_sigma = (const float*)d_in[0];
  const float* melspec  = (const float*)d_in[1];
  const int*   text_len = (const int*)d_in[2];
  const int*   mel_len  = (const int*)d_in[3];
  float* out = (float*)d_out;

  char* ws = (char*)d_ws;
  size_t off = 0;
  float* Wmat = (float*)(ws + off);      off += (size_t)B * KDIM * L * 4;  // 10.5 MB
  float* biasv = (float*)(ws + off);     off += (size_t)B * L * 4;
  float* carry_ws = (float*)(ws + off);  off += (size_t)B * L * 4;
  float* la_ws = (float*)(ws + off);     off += 256;
  unsigned short* logpT = (unsigned short*)(ws + off);
  size_t avail = (ws_size > off) ? (ws_size - off) : 0;
  size_t per_t = (size_t)B * L * 2;  // bytes per t-slice across all b (bf16)
  long long tcl = (long long)(avail / per_t);
  int Tc = (tcl > T) ? T : (int)tcl;
  Tc &= ~63;
  if (Tc < 64) return;  // insufficient workspace (not expected)

  prep_kernel<<<dim3((B * L + 255) / 256), 256, 0, stream>>>(mu_sigma, Wmat, biasv);

  for (int t_begin = 0; t_begin < T; t_begin += Tc) {
    int tc = (T - t_begin < Tc) ? (T - t_begin) : Tc;
    dim3 grid(tc / LT, L / LL, B);
    gemm_logp<<<grid, 256, 0, stream>>>(melspec, Wmat, biasv, mel_len, text_len,
                                        logpT, t_begin, tc);
    scan_kernel<<<dim3(B), 64, 0, stream>>>(logpT, mel_len, text_len, carry_ws,
                                            la_ws, t_begin, tc);
  }
  reduce_kernel<<<1, 64, 0, stream>>>(la_ws, out);
}

// Round 9
// 264.744 us; speedup vs baseline: 1.2939x; 1.2716x over previous
//
#include <hip/hip_runtime.h>
#include <hip/hip_bf16.h>
#include <cstdint>

#define B 32
#define L 512
#define T 2048
#define M 80
#define KDIM 160

#define NEG_INF (-1e30f)
#define LOG_2PI 1.8378770664093453f

typedef uint32_t u32;
typedef u32 u32x4 __attribute__((ext_vector_type(4)));

// robust to harness passing lengths as int32 or int64 (values are small positive;
// if int64, word[1] == high word of elem0 == 0; if int32, word[1] in [64,2048] != 0)
__device__ __forceinline__ int get_len(const int* __restrict__ p, int b) {
  return (p[1] == 0) ? p[2 * b] : p[b];
}

__device__ __forceinline__ unsigned short f2bf(float f) {
  __hip_bfloat16 h = __float2bfloat16(f);
  return *(unsigned short*)&h;
}

// ---------------- prep: Wmat[b][k][l], bias[b][l] ----------------
__global__ __launch_bounds__(256) void prep_kernel(const float* __restrict__ mu_sigma,
                                                   float* __restrict__ Wmat,
                                                   float* __restrict__ biasv) {
  int gid = blockIdx.x * 256 + threadIdx.x;  // b*L + l
  if (gid >= B * L) return;
  int b = gid >> 9;
  int l = gid & (L - 1);
  const float* row = mu_sigma + (size_t)gid * (2 * M);
  float* wb = Wmat + (size_t)b * KDIM * L + l;
  float acc_a = 0.f, acc_ls = 0.f;
#pragma unroll 4
  for (int m = 0; m < M; ++m) {
    float mu = row[m];
    float ls = row[M + m];
    float iv = expf(-2.f * ls);
    acc_a += mu * mu * iv;
    acc_ls += ls;
    wb[(size_t)m * L] = -0.5f * iv;
    wb[(size_t)(M + m) * L] = mu * iv;
  }
  biasv[gid] = -0.5f * acc_a - (0.5f * (float)M * LOG_2PI + 0.5f * acc_ls);
}

// ---------------- gemm: logpT[b][t][l] (bf16) = bias[l] + sum_k X[k][t]*W[k][l] ----
#define LT 64
#define LL 64
#define KC 40
__global__ __launch_bounds__(256) void gemm_logp(const float* __restrict__ x,
                                                 const float* __restrict__ Wmat,
                                                 const float* __restrict__ biasv,
                                                 const int* __restrict__ mel_len,
                                                 const int* __restrict__ text_len,
                                                 unsigned short* __restrict__ logpT,
                                                 int t_begin, int tc) {
  int b = blockIdx.z;
  int t0 = t_begin + blockIdx.x * LT;
  int l0 = blockIdx.y * LL;
  if (t0 >= get_len(mel_len, b)) return;
  if (l0 >= get_len(text_len, b)) return;

  __shared__ float Xs[KC][LT];
  __shared__ float Ws[KC][LL];
  int tid = threadIdx.x;
  int tx = tid & 15;   // t quad
  int ly = tid >> 4;   // l quad

  float acc[4][4];
#pragma unroll
  for (int i = 0; i < 4; ++i)
#pragma unroll
    for (int j = 0; j < 4; ++j) acc[i][j] = 0.f;

  for (int kc = 0; kc < KDIM; kc += KC) {
    bool sq = (kc < M);
#pragma unroll
    for (int p = 0; p < (KC * LT) / 256; ++p) {  // 10 passes
      int idx = p * 256 + tid;
      int kk = idx >> 6;
      int cc = idx & 63;
      int k = kc + kk;
      int m = sq ? k : (k - M);
      float xv = x[((size_t)b * M + m) * T + t0 + cc];
      Xs[kk][cc] = sq ? xv * xv : xv;
      Ws[kk][cc] = Wmat[((size_t)b * KDIM + k) * L + l0 + cc];
    }
    __syncthreads();
#pragma unroll 8
    for (int k = 0; k < KC; ++k) {
      float xa[4], wa[4];
#pragma unroll
      for (int i = 0; i < 4; ++i) xa[i] = Xs[k][tx * 4 + i];
#pragma unroll
      for (int j = 0; j < 4; ++j) wa[j] = Ws[k][ly * 4 + j];
#pragma unroll
      for (int i = 0; i < 4; ++i)
#pragma unroll
        for (int j = 0; j < 4; ++j) acc[i][j] += xa[i] * wa[j];
    }
    __syncthreads();
  }

  float bb[4];
#pragma unroll
  for (int j = 0; j < 4; ++j) bb[j] = biasv[b * L + l0 + ly * 4 + j];
#pragma unroll
  for (int i = 0; i < 4; ++i) {
    int t = t0 + tx * 4 + i;
    ushort4 o;
    o.x = f2bf(acc[i][0] + bb[0]);
    o.y = f2bf(acc[i][1] + bb[1]);
    o.z = f2bf(acc[i][2] + bb[2]);
    o.w = f2bf(acc[i][3] + bb[3]);
    *(ushort4*)(logpT + ((size_t)b * tc + (t - t_begin)) * L + l0 + ly * 4) = o;
  }
}

// ---------------- scan: register-direct bf16 pipeline ----------------
// Lane owns l = lane*8..lane*8+7 (one u32x4 = 8 bf16 per row). 3 blocks x 8
// rows of NAMED u32x4 (96 VGPR total - fits, unlike R7's fp32 192), loaded by
// inline-asm global_load_dwordx4 from a shared per-block base (+imm offsets),
// retired with counted vmcnt(23-r). No LDS, no lgkmcnt. DPP boundary.
#define GLDX4(dst, p, imm) \
  asm volatile("global_load_dwordx4 %0, %1, off offset:" #imm : "=v"(dst) : "v"(p))
#define VMW(n)                                             \
  do {                                                     \
    asm volatile("s_waitcnt vmcnt(" #n ")" ::: "memory");  \
    __builtin_amdgcn_sched_barrier(0);                     \
  } while (0)

#define DECL_BLK(P) u32x4 P##0, P##1, P##2, P##3, P##4, P##5, P##6, P##7

#define LOAD_BLK(P, plo_)              \
  do {                                 \
    const char* lo_ = (plo_);          \
    const char* hi_ = lo_ + 4096;      \
    GLDX4(P##0, lo_, 0);               \
    GLDX4(P##1, lo_, 1024);            \
    GLDX4(P##2, lo_, 2048);            \
    GLDX4(P##3, lo_, 3072);            \
    GLDX4(P##4, hi_, 0);               \
    GLDX4(P##5, hi_, 1024);            \
    GLDX4(P##6, hi_, 2048);            \
    GLDX4(P##7, hi_, 3072);            \
  } while (0)

#define COMP_BLK(P)          \
  do {                       \
    VMW(23); stepu(P##0);    \
    VMW(22); stepu(P##1);    \
    VMW(21); stepu(P##2);    \
    VMW(20); stepu(P##3);    \
    VMW(19); stepu(P##4);    \
    VMW(18); stepu(P##5);    \
    VMW(17); stepu(P##6);    \
    VMW(16); stepu(P##7);    \
  } while (0)

__device__ __forceinline__ float dpp_shr1_neginf(float x) {
  int r = __builtin_amdgcn_update_dpp(__float_as_int(NEG_INF), __float_as_int(x),
                                      0x138, 0xf, 0xf, false);  // wave_shr:1
  return __int_as_float(r);
}

__global__ __launch_bounds__(64) void scan_kernel(const unsigned short* __restrict__ logpT,
                                                  const int* __restrict__ mel_len,
                                                  const int* __restrict__ text_len,
                                                  float* __restrict__ carry_ws,
                                                  float* __restrict__ la_ws,
                                                  int t_begin, int tc) {
  int b = blockIdx.x;
  int lane = threadIdx.x;
  int ml = get_len(mel_len, b);
  int tl = get_len(text_len, b);
  const unsigned short* base0 = logpT + (size_t)b * tc * L;
  const char* laneBytes = (const char*)(base0 + lane * 8);
  float* cws = carry_ws + b * L + lane * 8;

  float c[8];
  int tstart;
  if (t_begin == 0) {
#pragma unroll
    for (int j = 0; j < 8; ++j) c[j] = NEG_INF;
    if (lane == 0) c[0] = __uint_as_float((u32)base0[0] << 16);  // logp[b,0,0]
    tstart = 1;
  } else {
    float4 v0 = *(const float4*)(cws);
    float4 v1 = *(const float4*)(cws + 4);
    c[0] = v0.x; c[1] = v0.y; c[2] = v0.z; c[3] = v0.w;
    c[4] = v1.x; c[5] = v1.y; c[6] = v1.z; c[7] = v1.w;
    tstart = t_begin;
  }

  int tstop = min(t_begin + tc, ml);

  auto stepu = [&](u32x4 v) {
    float p = dpp_shr1_neginf(c[7]);  // lane-1's old c[7]; lane0 <- NEG_INF
    float f0 = __uint_as_float(v[0] << 16);
    float f1 = __uint_as_float(v[0] & 0xFFFF0000u);
    float f2 = __uint_as_float(v[1] << 16);
    float f3 = __uint_as_float(v[1] & 0xFFFF0000u);
    float f4 = __uint_as_float(v[2] << 16);
    float f5 = __uint_as_float(v[2] & 0xFFFF0000u);
    float f6 = __uint_as_float(v[3] << 16);
    float f7 = __uint_as_float(v[3] & 0xFFFF0000u);
    c[7] = fmaxf(c[7], c[6]) + f7;
    c[6] = fmaxf(c[6], c[5]) + f6;
    c[5] = fmaxf(c[5], c[4]) + f5;
    c[4] = fmaxf(c[4], c[3]) + f4;
    c[3] = fmaxf(c[3], c[2]) + f3;
    c[2] = fmaxf(c[2], c[1]) + f2;
    c[1] = fmaxf(c[1], c[0]) + f1;
    c[0] = fmaxf(c[0], p) + f0;
  };

  int nrows = tstop - tstart;
  int nfull = 0;
  if (nrows > 0) {
    nfull = nrows >> 3;
    const char* p0 = laneBytes + (size_t)(tstart - t_begin) * (L * 2);
    if (nfull >= 3) {
      const char* pmax = p0 + (size_t)(nfull - 1) * 8192;
      DECL_BLK(A);
      DECL_BLK(Bb);
      DECL_BLK(Cc);
      LOAD_BLK(A, p0);
      LOAD_BLK(Bb, p0 + 8192);
      LOAD_BLK(Cc, p0 + 16384);
      const char* pload = p0 + 3 * 8192;
      if (pload > pmax) pload = pmax;
      int i = 0;
      for (;;) {
        COMP_BLK(A);
        if (++i == nfull) break;
        LOAD_BLK(A, pload);
        pload += 8192; if (pload > pmax) pload = pmax;
        COMP_BLK(Bb);
        if (++i == nfull) break;
        LOAD_BLK(Bb, pload);
        pload += 8192; if (pload > pmax) pload = pmax;
        COMP_BLK(Cc);
        if (++i == nfull) break;
        LOAD_BLK(Cc, pload);
        pload += 8192; if (pload > pmax) pload = pmax;
      }
      asm volatile("s_waitcnt vmcnt(0)" ::: "memory");  // drain dup prefetches
    } else {
      nfull = 0;
    }
    // tail rows (and the whole chunk when nfull < 3)
    for (int t = tstart + (nfull << 3); t < tstop; ++t) {
      u32x4 v = *(const u32x4*)(laneBytes + (size_t)(t - t_begin) * (L * 2));
      stepu(v);
    }
  }

  // persist carry for next chunk
  *(float4*)(cws) = make_float4(c[0], c[1], c[2], c[3]);
  *(float4*)(cws + 4) = make_float4(c[4], c[5], c[6], c[7]);

  if (t_begin + tc >= T) {  // last chunk: la[b] = alpha[ml-1][tl-1]
    int li = tl - 1;
    float csel = NEG_INF;
#pragma unroll
    for (int j = 0; j < 8; ++j)
      if ((li & 7) == j) csel = c[j];
    float lav = __shfl(csel, li >> 3);
    if (lane == 0) la_ws[b] = lav;
  }
}

__global__ __launch_bounds__(64) void reduce_kernel(const float* __restrict__ la_ws,
                                                    float* __restrict__ out) {
  int lane = threadIdx.x;
  float v = (lane < B) ? la_ws[lane] : 0.f;
#pragma unroll
  for (int s = 32; s > 0; s >>= 1) v += __shfl_down(v, s);
  if (lane == 0) out[0] = -v * (1.0f / (float)B);
}

extern "C" void kernel_launch(void* const* d_in, const int* in_sizes, int n_in,
                              void* d_out, int out_size, void* d_ws, size_t ws_size,
                              hipStream_t stream) {
  const float* mu_sigma = (const float*)d_in[0];
  const float* melspec  = (const float*)d_in[1];
  const int*   text_len = (const int*)d_in[2];
  const int*   mel_len  = (const int*)d_in[3];
  float* out = (float*)d_out;

  char* ws = (char*)d_ws;
  size_t off = 0;
  float* Wmat = (float*)(ws + off);      off += (size_t)B * KDIM * L * 4;  // 10.5 MB
  float* biasv = (float*)(ws + off);     off += (size_t)B * L * 4;
  float* carry_ws = (float*)(ws + off);  off += (size_t)B * L * 4;
  float* la_ws = (float*)(ws + off);     off += 256;
  unsigned short* logpT = (unsigned short*)(ws + off);
  size_t avail = (ws_size > off) ? (ws_size - off) : 0;
  size_t per_t = (size_t)B * L * 2;  // bytes per t-slice across all b (bf16)
  long long tcl = (long long)(avail / per_t);
  int Tc = (tcl > T) ? T : (int)tcl;
  Tc &= ~63;
  if (Tc < 64) return;  // insufficient workspace (not expected)

  prep_kernel<<<dim3((B * L + 255) / 256), 256, 0, stream>>>(mu_sigma, Wmat, biasv);

  for (int t_begin = 0; t_begin < T; t_begin += Tc) {
    int tc = (T - t_begin < Tc) ? (T - t_begin) : Tc;
    dim3 grid(tc / LT, L / LL, B);
    gemm_logp<<<grid, 256, 0, stream>>>(melspec, Wmat, biasv, mel_len, text_len,
                                        logpT, t_begin, tc);
    scan_kernel<<<dim3(B), 64, 0, stream>>>(logpT, mel_len, text_len, carry_ws,
                                            la_ws, t_begin, tc);
  }
  reduce_kernel<<<1, 64, 0, stream>>>(la_ws, out);
}

// Round 10
// 222.033 us; speedup vs baseline: 1.5428x; 1.1924x over previous
//
#include <hip/hip_runtime.h>
#include <hip/hip_bf16.h>
#include <cstdint>

#define B 32
#define L 512
#define T 2048
#define M 80
#define KDIM 160

#define NEG_INF (-1e30f)
#define LOG_2PI 1.8378770664093453f

typedef uint32_t u32;

// robust to harness passing lengths as int32 or int64 (values are small positive;
// if int64, word[1] == high word of elem0 == 0; if int32, word[1] in [64,2048] != 0)
__device__ __forceinline__ int get_len(const int* __restrict__ p, int b) {
  return (p[1] == 0) ? p[2 * b] : p[b];
}

__device__ __forceinline__ unsigned short f2bf(float f) {
  __hip_bfloat16 h = __float2bfloat16(f);
  return *(unsigned short*)&h;
}

// ---------------- prep: Wmat[b][k][l], bias[b][l] ----------------
__global__ __launch_bounds__(256) void prep_kernel(const float* __restrict__ mu_sigma,
                                                   float* __restrict__ Wmat,
                                                   float* __restrict__ biasv) {
  int gid = blockIdx.x * 256 + threadIdx.x;  // b*L + l
  if (gid >= B * L) return;
  int b = gid >> 9;
  int l = gid & (L - 1);
  const float* row = mu_sigma + (size_t)gid * (2 * M);
  float* wb = Wmat + (size_t)b * KDIM * L + l;
  float acc_a = 0.f, acc_ls = 0.f;
#pragma unroll 4
  for (int m = 0; m < M; ++m) {
    float mu = row[m];
    float ls = row[M + m];
    float iv = expf(-2.f * ls);
    acc_a += mu * mu * iv;
    acc_ls += ls;
    wb[(size_t)m * L] = -0.5f * iv;
    wb[(size_t)(M + m) * L] = mu * iv;
  }
  biasv[gid] = -0.5f * acc_a - (0.5f * (float)M * LOG_2PI + 0.5f * acc_ls);
}

// ---------------- gemm: logpT[b][t][l] (bf16) = bias[l] + sum_k X[k][t]*W[k][l] ----
#define LT 64
#define LL 64
#define KC 40
__global__ __launch_bounds__(256) void gemm_logp(const float* __restrict__ x,
                                                 const float* __restrict__ Wmat,
                                                 const float* __restrict__ biasv,
                                                 const int* __restrict__ mel_len,
                                                 const int* __restrict__ text_len,
                                                 unsigned short* __restrict__ logpT,
                                                 int t_begin, int tc) {
  int b = blockIdx.z;
  int t0 = t_begin + blockIdx.x * LT;
  int l0 = blockIdx.y * LL;
  if (t0 >= get_len(mel_len, b)) return;
  if (l0 >= get_len(text_len, b)) return;

  __shared__ float Xs[KC][LT];
  __shared__ float Ws[KC][LL];
  int tid = threadIdx.x;
  int tx = tid & 15;   // t quad
  int ly = tid >> 4;   // l quad

  float acc[4][4];
#pragma unroll
  for (int i = 0; i < 4; ++i)
#pragma unroll
    for (int j = 0; j < 4; ++j) acc[i][j] = 0.f;

  for (int kc = 0; kc < KDIM; kc += KC) {
    bool sq = (kc < M);
#pragma unroll
    for (int p = 0; p < (KC * LT) / 256; ++p) {  // 10 passes
      int idx = p * 256 + tid;
      int kk = idx >> 6;
      int cc = idx & 63;
      int k = kc + kk;
      int m = sq ? k : (k - M);
      float xv = x[((size_t)b * M + m) * T + t0 + cc];
      Xs[kk][cc] = sq ? xv * xv : xv;
      Ws[kk][cc] = Wmat[((size_t)b * KDIM + k) * L + l0 + cc];
    }
    __syncthreads();
#pragma unroll 8
    for (int k = 0; k < KC; ++k) {
      float xa[4], wa[4];
#pragma unroll
      for (int i = 0; i < 4; ++i) xa[i] = Xs[k][tx * 4 + i];
#pragma unroll
      for (int j = 0; j < 4; ++j) wa[j] = Ws[k][ly * 4 + j];
#pragma unroll
      for (int i = 0; i < 4; ++i)
#pragma unroll
        for (int j = 0; j < 4; ++j) acc[i][j] += xa[i] * wa[j];
    }
    __syncthreads();
  }

  float bb[4];
#pragma unroll
  for (int j = 0; j < 4; ++j) bb[j] = biasv[b * L + l0 + ly * 4 + j];
#pragma unroll
  for (int i = 0; i < 4; ++i) {
    int t = t0 + tx * 4 + i;
    ushort4 o;
    o.x = f2bf(acc[i][0] + bb[0]);
    o.y = f2bf(acc[i][1] + bb[1]);
    o.z = f2bf(acc[i][2] + bb[2]);
    o.w = f2bf(acc[i][3] + bb[3]);
    *(ushort4*)(logpT + ((size_t)b * tc + (t - t_begin)) * L + l0 + ly * 4) = o;
  }
}

// ---------------- scan: 7 waves per batch, halo-redundant max-plus ----------------
// Dataflow is strictly left-to-right (alpha[t][l] <- l, l-1). Wave w covers cols
// [64w, 64w+128) (2 cols/lane, bf16 row data, 1 dword/lane/row); it OWNS the top
// 64 (wave0 owns all 128); the bottom 64 are a redundant halo that degrades 1
// col/step. Every 64 steps waves exchange owned->halo via LDS + one barrier
// (parity double-buffered). Register pipeline: 3 blocks x 8 rows of named u32
// (~45 VGPR - cannot spill), counted vmcnt(23-r). DPP wave_shr for in-wave
// boundary (lane0 <- NEG_INF == halo left edge).
#define GLDW(dst, p, imm) \
  asm volatile("global_load_dword %0, %1, off offset:" #imm : "=v"(dst) : "v"(p))
#define VMW(n)                                             \
  do {                                                     \
    asm volatile("s_waitcnt vmcnt(" #n ")" ::: "memory");  \
    __builtin_amdgcn_sched_barrier(0);                     \
  } while (0)

#define DECL_BLK8(P) u32 P##0, P##1, P##2, P##3, P##4, P##5, P##6, P##7
#define LOAD_BLK8(P, plo_)             \
  do {                                 \
    const char* lo_ = (plo_);          \
    const char* hi_ = lo_ + 4096;      \
    GLDW(P##0, lo_, 0);                \
    GLDW(P##1, lo_, 1024);             \
    GLDW(P##2, lo_, 2048);             \
    GLDW(P##3, lo_, 3072);             \
    GLDW(P##4, hi_, 0);                \
    GLDW(P##5, hi_, 1024);             \
    GLDW(P##6, hi_, 2048);             \
    GLDW(P##7, hi_, 3072);             \
  } while (0)
#define COMP_BLK8(P)         \
  do {                       \
    VMW(23); stepu(P##0);    \
    VMW(22); stepu(P##1);    \
    VMW(21); stepu(P##2);    \
    VMW(20); stepu(P##3);    \
    VMW(19); stepu(P##4);    \
    VMW(18); stepu(P##5);    \
    VMW(17); stepu(P##6);    \
    VMW(16); stepu(P##7);    \
  } while (0)

__device__ __forceinline__ float dpp_shr1_neginf(float x) {
  int r = __builtin_amdgcn_update_dpp(__float_as_int(NEG_INF), __float_as_int(x),
                                      0x138, 0xf, 0xf, false);  // wave_shr:1
  return __int_as_float(r);
}

__global__ __launch_bounds__(448, 2) void scan_kernel(const unsigned short* __restrict__ logpT,
                                                      const int* __restrict__ mel_len,
                                                      const int* __restrict__ text_len,
                                                      float* __restrict__ carry_ws,
                                                      float* __restrict__ la_ws,
                                                      int t_begin, int tc) {
  __shared__ float smem[2][512];
  int tid = threadIdx.x;
  int wave = tid >> 6;
  int lane = tid & 63;
  int b = blockIdx.x;
  int ml = get_len(mel_len, b);
  int tl = get_len(text_len, b);
  const unsigned short* base0 = logpT + (size_t)b * tc * L;
  const char* laneB = (const char*)base0 + 128 * wave + 4 * lane;
  float* cws = carry_ws + b * L;
  int col0 = 64 * wave + 2 * lane;               // col of c0 (c1 = col0+1)
  bool owner = (wave == 0) || (lane >= 32);      // owns cols col0, col0+1

  float c0, c1;
  int tstart;
  if (t_begin == 0) {
    c0 = NEG_INF; c1 = NEG_INF;
    if (tid == 0) c0 = __uint_as_float((u32)base0[0] << 16);  // logp[b,0,0]
    tstart = 1;
  } else {
    float2 v = *(const float2*)(cws + col0);
    c0 = v.x; c1 = v.y;
    tstart = t_begin;
  }

  int tstop = min(t_begin + tc, ml);
  int sidx = 0;

  auto stepu = [&](u32 v) {
    float p = dpp_shr1_neginf(c1);  // lane-1's old c1; lane0 <- NEG_INF (halo edge)
    float f0 = __uint_as_float(v << 16);
    float f1 = __uint_as_float(v & 0xFFFF0000u);
    c1 = fmaxf(c1, c0) + f1;
    c0 = fmaxf(c0, p) + f0;
  };

  auto dosync = [&]() {  // refresh halos from owners; one barrier, parity dbuf
    int par = sidx & 1;
    ++sidx;
    if (owner) {
      smem[par][col0] = c0;
      smem[par][col0 + 1] = c1;
    }
    __syncthreads();
    if (wave > 0 && lane < 32) {
      c0 = smem[par][col0];
      c1 = smem[par][col0 + 1];
    }
  };

  int nrows = tstop - tstart;
  if (nrows > 0) {
    int nfull = nrows >> 3;
    const char* p0 = laneB + (size_t)(tstart - t_begin) * 1024;
    if (nfull >= 3) {
      const char* pmax = p0 + (size_t)(nfull - 1) * 8192;
      DECL_BLK8(A);
      DECL_BLK8(Bb);
      DECL_BLK8(Cc);
      LOAD_BLK8(A, p0);
      LOAD_BLK8(Bb, p0 + 8192);
      LOAD_BLK8(Cc, p0 + 16384);
      const char* pload = p0 + 3 * 8192;
      if (pload > pmax) pload = pmax;
      int i = 0;
      for (;;) {
        COMP_BLK8(A);
        ++i; if ((i & 7) == 0) dosync();
        if (i == nfull) break;
        LOAD_BLK8(A, pload);
        pload += 8192; if (pload > pmax) pload = pmax;
        COMP_BLK8(Bb);
        ++i; if ((i & 7) == 0) dosync();
        if (i == nfull) break;
        LOAD_BLK8(Bb, pload);
        pload += 8192; if (pload > pmax) pload = pmax;
        COMP_BLK8(Cc);
        ++i; if ((i & 7) == 0) dosync();
        if (i == nfull) break;
        LOAD_BLK8(Cc, pload);
        pload += 8192; if (pload > pmax) pload = pmax;
      }
      asm volatile("s_waitcnt vmcnt(0)" ::: "memory");  // drain dup prefetches
    } else {
      nfull = 0;
    }
    // tail rows (< 8, and whole chunk when nfull < 3; staleness stays < 64)
    for (int t = tstart + (nfull << 3); t < tstop; ++t) {
      u32 v = *(const u32*)(laneB + (size_t)(t - t_begin) * 1024);
      stepu(v);
    }
  }

  // persist carry (owned cols only)
  if (owner) *(float2*)(cws + col0) = make_float2(c0, c1);

  if (t_begin + tc >= T) {  // last chunk: la[b] = alpha[ml-1][tl-1]
    int li = tl - 1;
    int w_own = (li < 128) ? 0 : ((li >> 6) - 1);
    if (wave == w_own) {
      int local = li - 64 * w_own;
      float v = (local & 1) ? c1 : c0;
      float lav = __shfl(v, local >> 1);
      if (lane == 0) la_ws[b] = lav;
    }
  }
}

__global__ __launch_bounds__(64) void reduce_kernel(const float* __restrict__ la_ws,
                                                    float* __restrict__ out) {
  int lane = threadIdx.x;
  float v = (lane < B) ? la_ws[lane] : 0.f;
#pragma unroll
  for (int s = 32; s > 0; s >>= 1) v += __shfl_down(v, s);
  if (lane == 0) out[0] = -v * (1.0f / (float)B);
}

extern "C" void kernel_launch(void* const* d_in, const int* in_sizes, int n_in,
                              void* d_out, int out_size, void* d_ws, size_t ws_size,
                              hipStream_t stream) {
  const float* mu_sigma = (const float*)d_in[0];
  const float* melspec  = (const float*)d_in[1];
  const int*   text_len = (const int*)d_in[2];
  const int*   mel_len  = (const int*)d_in[3];
  float* out = (float*)d_out;

  char* ws = (char*)d_ws;
  size_t off = 0;
  float* Wmat = (float*)(ws + off);      off += (size_t)B * KDIM * L * 4;  // 10.5 MB
  float* biasv = (float*)(ws + off);     off += (size_t)B * L * 4;
  float* carry_ws = (float*)(ws + off);  off += (size_t)B * L * 4;
  float* la_ws = (float*)(ws + off);     off += 256;
  unsigned short* logpT = (unsigned short*)(ws + off);
  size_t avail = (ws_size > off) ? (ws_size - off) : 0;
  size_t per_t = (size_t)B * L * 2;  // bytes per t-slice across all b (bf16)
  long long tcl = (long long)(avail / per_t);
  int Tc = (tcl > T) ? T : (int)tcl;
  Tc &= ~63;
  if (Tc < 64) return;  // insufficient workspace (not expected)

  prep_kernel<<<dim3((B * L + 255) / 256), 256, 0, stream>>>(mu_sigma, Wmat, biasv);

  for (int t_begin = 0; t_begin < T; t_begin += Tc) {
    int tc = (T - t_begin < Tc) ? (T - t_begin) : Tc;
    dim3 grid(tc / LT, L / LL, B);
    gemm_logp<<<grid, 256, 0, stream>>>(melspec, Wmat, biasv, mel_len, text_len,
                                        logpT, t_begin, tc);
    scan_kernel<<<dim3(B), 448, 0, stream>>>(logpT, mel_len, text_len, carry_ws,
                                             la_ws, t_begin, tc);
  }
  reduce_kernel<<<1, 64, 0, stream>>>(la_ws, out);
}

// Round 11
// 137.903 us; speedup vs baseline: 2.4840x; 1.6101x over previous
//
#include <hip/hip_runtime.h>
#include <hip/hip_bf16.h>
#include <cstdint>

#define B 32
#define L 512
#define T 2048
#define M 80
#define KDIM 160

#define NEG_INF (-1e30f)
#define LOG_2PI 1.8378770664093453f

typedef uint32_t u32;
typedef unsigned short u16;
typedef u16 u16x8 __attribute__((ext_vector_type(8)));
typedef short bf16x8 __attribute__((ext_vector_type(8)));
typedef float f32x4 __attribute__((ext_vector_type(4)));

// robust to harness passing lengths as int32 or int64 (values are small positive;
// if int64, word[1] == high word of elem0 == 0; if int32, word[1] in [64,2048] != 0)
__device__ __forceinline__ int get_len(const int* __restrict__ p, int b) {
  return (p[1] == 0) ? p[2 * b] : p[b];
}

__device__ __forceinline__ u16 f2bf(float f) {
  __hip_bfloat16 h = __float2bfloat16(f);
  return *(u16*)&h;
}

// ---------------- prep: Wfrag[b][kc][l][8] (bf16 B-fragments), bias[b][l] --------
// k in [0,80):  W = -0.5*inv_var (pairs with x^2); k in [80,160): W = mu*inv_var.
__global__ __launch_bounds__(256) void prep_kernel(const float* __restrict__ mu_sigma,
                                                   u16* __restrict__ Wfrag,
                                                   float* __restrict__ biasv) {
  int gid = blockIdx.x * 256 + threadIdx.x;  // b*L + l
  if (gid >= B * L) return;
  int b = gid >> 9;
  int l = gid & (L - 1);
  const float* row = mu_sigma + (size_t)gid * (2 * M);
  float acc_a = 0.f, acc_ls = 0.f;
#pragma unroll 2
  for (int g = 0; g < 10; ++g) {
    u16x8 wsq, wli;
#pragma unroll
    for (int j = 0; j < 8; ++j) {
      float mu = row[g * 8 + j];
      float ls = row[M + g * 8 + j];
      float iv = expf(-2.f * ls);
      acc_a += mu * mu * iv;
      acc_ls += ls;
      wsq[j] = f2bf(-0.5f * iv);
      wli[j] = f2bf(mu * iv);
    }
    *(u16x8*)(Wfrag + ((size_t)(b * 20 + g) * L + l) * 8) = wsq;
    *(u16x8*)(Wfrag + ((size_t)(b * 20 + 10 + g) * L + l) * 8) = wli;
  }
  biasv[gid] = -0.5f * acc_a - (0.5f * (float)M * LOG_2PI + 0.5f * acc_ls);
}

// ---------------- xprep: Xfrag[b][kc][t][8] (bf16 A-fragments) ----------------
// kc in [0,10): x^2 of mel group kc; kc in [10,20): x of mel group kc-10.
__global__ __launch_bounds__(256) void xprep_kernel(const float* __restrict__ melspec,
                                                    u16* __restrict__ Xfrag) {
  int gid = blockIdx.x * 256 + threadIdx.x;  // (b*10 + mg)*T + t
  int t = gid & (T - 1);
  int rest = gid >> 11;
  int mg = rest % 10;
  int b = rest / 10;
  u16x8 sq, li;
#pragma unroll
  for (int j = 0; j < 8; ++j) {
    float xv = melspec[((size_t)b * M + mg * 8 + j) * T + t];
    sq[j] = f2bf(xv * xv);
    li[j] = f2bf(xv);
  }
  *(u16x8*)(Xfrag + ((size_t)(b * 20 + mg) * T + t) * 8) = sq;
  *(u16x8*)(Xfrag + ((size_t)(b * 20 + 10 + mg) * T + t) * 8) = li;
}

// ---------------- gemm (MFMA): logpT[b][t][l] bf16 = bias + sum_k X*W ----------
// Block 64t x 128l, 4 waves (2x2), wave = 2 m-tiles x 4 n-tiles of 16x16,
// K = 160 = 5 steps of mfma_f32_16x16x32_bf16. Operands pre-swizzled so each
// lane's fragment is one contiguous 16B load (khalf=lane>>4 selects kc).
__global__ __launch_bounds__(256) void gemm_logp(const u16* __restrict__ Xfrag,
                                                 const u16* __restrict__ Wfrag,
                                                 const float* __restrict__ biasv,
                                                 const int* __restrict__ mel_len,
                                                 const int* __restrict__ text_len,
                                                 u16* __restrict__ logpT,
                                                 int t_begin, int tc) {
  int b = blockIdx.z;
  int t0 = t_begin + blockIdx.x * 64;
  int l0 = blockIdx.y * 128;
  if (t0 >= get_len(mel_len, b)) return;
  if (l0 >= get_len(text_len, b)) return;

  int tid = threadIdx.x;
  int wave = tid >> 6, lane = tid & 63;
  int wt = wave >> 1, wl = wave & 1;
  int mbase = t0 + wt * 32;
  int nbase = l0 + wl * 64;
  int l16 = lane & 15, khalf = lane >> 4;

  const bf16x8* Xp = (const bf16x8*)Xfrag;
  const bf16x8* Wp = (const bf16x8*)Wfrag;

  f32x4 acc[2][4];
#pragma unroll
  for (int i = 0; i < 2; ++i)
#pragma unroll
    for (int j = 0; j < 4; ++j) acc[i][j] = (f32x4){0.f, 0.f, 0.f, 0.f};

#pragma unroll
  for (int ks = 0; ks < 5; ++ks) {
    int kc = ks * 4 + khalf;
    size_t xb = (size_t)(b * 20 + kc) * T;
    size_t wb = (size_t)(b * 20 + kc) * L;
    bf16x8 a0 = Xp[xb + mbase + l16];
    bf16x8 a1 = Xp[xb + mbase + 16 + l16];
    bf16x8 b0 = Wp[wb + nbase + l16];
    bf16x8 b1 = Wp[wb + nbase + 16 + l16];
    bf16x8 b2 = Wp[wb + nbase + 32 + l16];
    bf16x8 b3 = Wp[wb + nbase + 48 + l16];
    acc[0][0] = __builtin_amdgcn_mfma_f32_16x16x32_bf16(a0, b0, acc[0][0], 0, 0, 0);
    acc[0][1] = __builtin_amdgcn_mfma_f32_16x16x32_bf16(a0, b1, acc[0][1], 0, 0, 0);
    acc[0][2] = __builtin_amdgcn_mfma_f32_16x16x32_bf16(a0, b2, acc[0][2], 0, 0, 0);
    acc[0][3] = __builtin_amdgcn_mfma_f32_16x16x32_bf16(a0, b3, acc[0][3], 0, 0, 0);
    acc[1][0] = __builtin_amdgcn_mfma_f32_16x16x32_bf16(a1, b0, acc[1][0], 0, 0, 0);
    acc[1][1] = __builtin_amdgcn_mfma_f32_16x16x32_bf16(a1, b1, acc[1][1], 0, 0, 0);
    acc[1][2] = __builtin_amdgcn_mfma_f32_16x16x32_bf16(a1, b2, acc[1][2], 0, 0, 0);
    acc[1][3] = __builtin_amdgcn_mfma_f32_16x16x32_bf16(a1, b3, acc[1][3], 0, 0, 0);
  }

  // epilogue: C/D map col = lane&15, row = khalf*4 + r  [verified m89/m91]
  int rbase = khalf * 4;
#pragma unroll
  for (int j = 0; j < 4; ++j) {
    int colL = nbase + j * 16 + l16;
    float bias = biasv[b * L + colL];
#pragma unroll
    for (int i = 0; i < 2; ++i) {
#pragma unroll
      for (int r = 0; r < 4; ++r) {
        int t = mbase + i * 16 + rbase + r;
        logpT[((size_t)b * tc + (t - t_begin)) * L + colL] = f2bf(acc[i][j][r] + bias);
      }
    }
  }
}

// ---------------- scan: 7 waves per batch, halo-redundant max-plus ----------------
#define GLDW(dst, p, imm) \
  asm volatile("global_load_dword %0, %1, off offset:" #imm : "=v"(dst) : "v"(p))
#define VMW(n)                                             \
  do {                                                     \
    asm volatile("s_waitcnt vmcnt(" #n ")" ::: "memory");  \
    __builtin_amdgcn_sched_barrier(0);                     \
  } while (0)

#define DECL_BLK8(P) u32 P##0, P##1, P##2, P##3, P##4, P##5, P##6, P##7
#define LOAD_BLK8(P, plo_)             \
  do {                                 \
    const char* lo_ = (plo_);          \
    const char* hi_ = lo_ + 4096;      \
    GLDW(P##0, lo_, 0);                \
    GLDW(P##1, lo_, 1024);             \
    GLDW(P##2, lo_, 2048);             \
    GLDW(P##3, lo_, 3072);             \
    GLDW(P##4, hi_, 0);                \
    GLDW(P##5, hi_, 1024);             \
    GLDW(P##6, hi_, 2048);             \
    GLDW(P##7, hi_, 3072);             \
  } while (0)
#define COMP_BLK8(P)         \
  do {                       \
    VMW(23); stepu(P##0);    \
    VMW(22); stepu(P##1);    \
    VMW(21); stepu(P##2);    \
    VMW(20); stepu(P##3);    \
    VMW(19); stepu(P##4);    \
    VMW(18); stepu(P##5);    \
    VMW(17); stepu(P##6);    \
    VMW(16); stepu(P##7);    \
  } while (0)

__device__ __forceinline__ float dpp_shr1_neginf(float x) {
  int r = __builtin_amdgcn_update_dpp(__float_as_int(NEG_INF), __float_as_int(x),
                                      0x138, 0xf, 0xf, false);  // wave_shr:1
  return __int_as_float(r);
}

__global__ __launch_bounds__(448, 2) void scan_kernel(const u16* __restrict__ logpT,
                                                      const int* __restrict__ mel_len,
                                                      const int* __restrict__ text_len,
                                                      float* __restrict__ carry_ws,
                                                      float* __restrict__ la_ws,
                                                      int t_begin, int tc) {
  __shared__ float smem[2][512];
  int tid = threadIdx.x;
  int wave = tid >> 6;
  int lane = tid & 63;
  int b = blockIdx.x;
  int ml = get_len(mel_len, b);
  int tl = get_len(text_len, b);
  const u16* base0 = logpT + (size_t)b * tc * L;
  const char* laneB = (const char*)base0 + 128 * wave + 4 * lane;
  float* cws = carry_ws + b * L;
  int col0 = 64 * wave + 2 * lane;               // col of c0 (c1 = col0+1)
  bool owner = (wave == 0) || (lane >= 32);      // owns cols col0, col0+1

  float c0, c1;
  int tstart;
  if (t_begin == 0) {
    c0 = NEG_INF; c1 = NEG_INF;
    if (tid == 0) c0 = __uint_as_float((u32)base0[0] << 16);  // logp[b,0,0]
    tstart = 1;
  } else {
    float2 v = *(const float2*)(cws + col0);
    c0 = v.x; c1 = v.y;
    tstart = t_begin;
  }

  int tstop = min(t_begin + tc, ml);
  int sidx = 0;

  auto stepu = [&](u32 v) {
    float p = dpp_shr1_neginf(c1);  // lane-1's old c1; lane0 <- NEG_INF (halo edge)
    float f0 = __uint_as_float(v << 16);
    float f1 = __uint_as_float(v & 0xFFFF0000u);
    c1 = fmaxf(c1, c0) + f1;
    c0 = fmaxf(c0, p) + f0;
  };

  auto dosync = [&]() {  // refresh halos from owners; one barrier, parity dbuf
    int par = sidx & 1;
    ++sidx;
    if (owner) {
      smem[par][col0] = c0;
      smem[par][col0 + 1] = c1;
    }
    __syncthreads();
    if (wave > 0 && lane < 32) {
      c0 = smem[par][col0];
      c1 = smem[par][col0 + 1];
    }
  };

  int nrows = tstop - tstart;
  if (nrows > 0) {
    int nfull = nrows >> 3;
    const char* p0 = laneB + (size_t)(tstart - t_begin) * 1024;
    if (nfull >= 3) {
      const char* pmax = p0 + (size_t)(nfull - 1) * 8192;
      DECL_BLK8(A);
      DECL_BLK8(Bb);
      DECL_BLK8(Cc);
      LOAD_BLK8(A, p0);
      LOAD_BLK8(Bb, p0 + 8192);
      LOAD_BLK8(Cc, p0 + 16384);
      const char* pload = p0 + 3 * 8192;
      if (pload > pmax) pload = pmax;
      int i = 0;
      for (;;) {
        COMP_BLK8(A);
        ++i; if ((i & 7) == 0) dosync();
        if (i == nfull) break;
        LOAD_BLK8(A, pload);
        pload += 8192; if (pload > pmax) pload = pmax;
        COMP_BLK8(Bb);
        ++i; if ((i & 7) == 0) dosync();
        if (i == nfull) break;
        LOAD_BLK8(Bb, pload);
        pload += 8192; if (pload > pmax) pload = pmax;
        COMP_BLK8(Cc);
        ++i; if ((i & 7) == 0) dosync();
        if (i == nfull) break;
        LOAD_BLK8(Cc, pload);
        pload += 8192; if (pload > pmax) pload = pmax;
      }
      asm volatile("s_waitcnt vmcnt(0)" ::: "memory");  // drain dup prefetches
    } else {
      nfull = 0;
    }
    // tail rows (< 8, and whole chunk when nfull < 3; staleness stays < 64)
    for (int t = tstart + (nfull << 3); t < tstop; ++t) {
      u32 v = *(const u32*)(laneB + (size_t)(t - t_begin) * 1024);
      stepu(v);
    }
  }

  // persist carry (owned cols only)
  if (owner) *(float2*)(cws + col0) = make_float2(c0, c1);

  if (t_begin + tc >= T) {  // last chunk: la[b] = alpha[ml-1][tl-1]
    int li = tl - 1;
    int w_own = (li < 128) ? 0 : ((li >> 6) - 1);
    if (wave == w_own) {
      int local = li - 64 * w_own;
      float v = (local & 1) ? c1 : c0;
      float lav = __shfl(v, local >> 1);
      if (lane == 0) la_ws[b] = lav;
    }
  }
}

__global__ __launch_bounds__(64) void reduce_kernel(const float* __restrict__ la_ws,
                                                    float* __restrict__ out) {
  int lane = threadIdx.x;
  float v = (lane < B) ? la_ws[lane] : 0.f;
#pragma unroll
  for (int s = 32; s > 0; s >>= 1) v += __shfl_down(v, s);
  if (lane == 0) out[0] = -v * (1.0f / (float)B);
}

extern "C" void kernel_launch(void* const* d_in, const int* in_sizes, int n_in,
                              void* d_out, int out_size, void* d_ws, size_t ws_size,
                              hipStream_t stream) {
  const float* mu_sigma = (const float*)d_in[0];
  const float* melspec  = (const float*)d_in[1];
  const int*   text_len = (const int*)d_in[2];
  const int*   mel_len  = (const int*)d_in[3];
  float* out = (float*)d_out;

  char* ws = (char*)d_ws;
  size_t off = 0;
  u16* Wfrag = (u16*)(ws + off);         off += (size_t)B * KDIM * L * 2;      // 5.2 MB
  float* biasv = (float*)(ws + off);     off += (size_t)B * L * 4;
  float* carry_ws = (float*)(ws + off);  off += (size_t)B * L * 4;
  float* la_ws = (float*)(ws + off);     off += 256;
  u16* Xfrag = (u16*)(ws + off);         off += (size_t)B * KDIM * T * 2;      // 21 MB
  u16* logpT = (u16*)(ws + off);
  size_t avail = (ws_size > off) ? (ws_size - off) : 0;
  size_t per_t = (size_t)B * L * 2;  // bytes per t-slice across all b (bf16)
  long long tcl = (long long)(avail / per_t);
  int Tc = (tcl > T) ? T : (int)tcl;
  Tc &= ~63;
  if (Tc < 64) return;  // insufficient workspace (not expected)

  prep_kernel<<<dim3((B * L + 255) / 256), 256, 0, stream>>>(mu_sigma, Wfrag, biasv);
  xprep_kernel<<<dim3((B * 10 * T) / 256), 256, 0, stream>>>(melspec, Xfrag);

  for (int t_begin = 0; t_begin < T; t_begin += Tc) {
    int tc = (T - t_begin < Tc) ? (T - t_begin) : Tc;
    dim3 grid(tc / 64, L / 128, B);
    gemm_logp<<<grid, 256, 0, stream>>>(Xfrag, Wfrag, biasv, mel_len, text_len,
                                        logpT, t_begin, tc);
    scan_kernel<<<dim3(B), 448, 0, stream>>>(logpT, mel_len, text_len, carry_ws,
                                             la_ws, t_begin, tc);
  }
  reduce_kernel<<<1, 64, 0, stream>>>(la_ws, out);
}